// Round 13
// baseline (213.711 us; speedup 1.0000x reference)
//
#include <hip/hip_runtime.h>
#include <math.h>

#define B_SZ   2
#define T_SEQ  2048
#define NH     16
#define HDIM   64
#define D_MOD  1024
#define DL     512
#define DC     256
#define MROWS  4096   // B*T

typedef __attribute__((ext_vector_type(8))) short bf16x8;
typedef __attribute__((ext_vector_type(4))) float f32x4;

#define SCALE_Q 0.18033688011112042f   // (1/sqrt(64)) * log2(e)

static __device__ __forceinline__ unsigned short f2bf(float f) {
    union { float f; unsigned u; } v; v.f = f;
    unsigned r = v.u + 0x7fffu + ((v.u >> 16) & 1u);   // RNE
    return (unsigned short)(r >> 16);
}

// async global->LDS, 16B per lane; lds base wave-uniform, lane i -> base+i*16.
static __device__ __forceinline__ void gl_lds16(const unsigned short* g,
                                                unsigned short* l) {
    __builtin_amdgcn_global_load_lds(
        (const __attribute__((address_space(1))) unsigned int*)g,
        (__attribute__((address_space(3))) unsigned int*)l, 16, 0, 0);
}

// ---------------------------------------------------------------------------
// Convert x + weights fp32 -> bf16 (W_exp transposed: its only consumer is
// the wcomb GEMM which needs [c][l]), and build RoPE table [T,32] (cos,sin).
// ---------------------------------------------------------------------------
__global__ __launch_bounds__(256) void cvt_bf16(
    const float* __restrict__ x,  const float* __restrict__ wq,
    const float* __restrict__ wkvl, const float* __restrict__ wcomp,
    const float* __restrict__ wexp, const float* __restrict__ wfkv,
    const float* __restrict__ wout,
    unsigned short* __restrict__ xb,  unsigned short* __restrict__ wqh,
    unsigned short* __restrict__ wkvlh, unsigned short* __restrict__ wcomph,
    unsigned short* __restrict__ wexpTh, unsigned short* __restrict__ wfkvh,
    unsigned short* __restrict__ wouth, float2* __restrict__ rope_tab)
{
    const int g = blockIdx.x * 256 + threadIdx.x;
    const int stride = gridDim.x * 256;
#define CVT_SEG(src, dst, n4)                                              \
    for (int i = g; i < (n4); i += stride) {                               \
        float4 v = ((const float4*)(src))[i];                              \
        unsigned short h[4] = {f2bf(v.x), f2bf(v.y), f2bf(v.z), f2bf(v.w)};\
        *(uint2*)((dst) + (size_t)i * 4) = *(uint2*)h;                     \
    }
    CVT_SEG(x, xb, 1048576)
    CVT_SEG(wq, wqh, 262144)
    CVT_SEG(wkvl, wkvlh, 131072)
    CVT_SEG(wcomp, wcomph, 32768)
    CVT_SEG(wfkv, wfkvh, 262144)
    CVT_SEG(wout, wouth, 262144)
#undef CVT_SEG
    // W_exp [512(l)][256(c)] fp32 -> wexpTh [256(c)][512(l)] bf16.
    // i = c*128 + l4; writes coalesced (8B), reads strided (L2-small tensor).
    for (int i = g; i < 32768; i += stride) {
        const int c = i >> 7, l4 = (i & 127) << 2;
        unsigned short h[4];
#pragma unroll
        for (int r = 0; r < 4; ++r)
            h[r] = f2bf(wexp[(size_t)(l4 + r) * DC + c]);
        *(uint2*)(wexpTh + (size_t)c * DL + l4) = *(uint2*)h;
    }
    for (int i = g; i < T_SEQ * 32; i += stride) {
        const int t = i >> 5, fi = i & 31;
        const float inv = __expf((float)fi * (-9.210340371976184f / 32.0f));
        float sn, cs; sincosf((float)t * inv, &sn, &cs);
        rope_tab[i] = make_float2(cs, sn);
    }
}

// ===========================================================================
// 64x64-tile bf16 MFMA GEMM, BK=64, XOR-swizzled LDS, 2-phase dbuf pipeline.
// [r13: neutral vs 2-barrier — kept. r10: 128^2 regressed at 1-2 blocks/CU.]
// ===========================================================================
#define GEMM64P_PROLOG(Aptr, Wptr, Kdim)                                       \
    __shared__ unsigned short As[2][64 * 64];                                  \
    __shared__ unsigned short Ws[2][64 * 64];                                  \
    const int tid = threadIdx.x;                                               \
    const int w = tid >> 6, lane = tid & 63;                                   \
    const int l16 = lane & 15, quad = lane >> 4;                               \
    const int sw8 = ((lane & 7) ^ ((lane >> 3) & 7)) << 3;                     \
    const int srow = lane >> 3;                                                \
    const unsigned short* Ag0 = (Aptr) + (size_t)(m0 + w * 16 + srow) * (Kdim) + sw8;      \
    const unsigned short* Ag1 = Ag0 + (size_t)8 * (Kdim);                      \
    const unsigned short* Wg0 = (Wptr) + (size_t)(n0 + w * 16 + srow) * (Kdim) + sw8;      \
    const unsigned short* Wg1 = Wg0 + (size_t)8 * (Kdim);                      \
    const int aoff = (w * 16) * 64;                                            \
    const int xh = (l16 & 7);                                                  \
    f32x4 acc[4];                                                              \
    _Pragma("unroll") for (int j = 0; j < 4; ++j)                              \
        acc[j] = (f32x4){0.f, 0.f, 0.f, 0.f};                                  \
    gl_lds16(Ag0, &As[0][aoff]);                                               \
    gl_lds16(Ag1, &As[0][aoff + 512]);                                         \
    gl_lds16(Wg0, &Ws[0][aoff]);                                               \
    gl_lds16(Wg1, &Ws[0][aoff + 512]);                                         \
    for (int k0 = 0, buf = 0; k0 < (Kdim); k0 += 64, buf ^= 1) {               \
        if (k0 + 64 < (Kdim)) {                                                \
            gl_lds16(Ag0 + k0 + 64, &As[buf ^ 1][aoff]);                       \
            gl_lds16(Ag1 + k0 + 64, &As[buf ^ 1][aoff + 512]);                 \
            gl_lds16(Wg0 + k0 + 64, &Ws[buf ^ 1][aoff]);                       \
            gl_lds16(Wg1 + k0 + 64, &Ws[buf ^ 1][aoff + 512]);                 \
            asm volatile("s_waitcnt vmcnt(4)" ::: "memory");                   \
        } else {                                                               \
            asm volatile("s_waitcnt vmcnt(0)" ::: "memory");                   \
        }                                                                      \
        __builtin_amdgcn_s_barrier();                                          \
        bf16x8 af[2], bfr[4][2];                                               \
        _Pragma("unroll") for (int kk = 0; kk < 2; ++kk)                       \
            af[kk] = *(const bf16x8*)&As[buf][(w * 16 + l16) * 64 +            \
                                         (((kk * 4 + quad) ^ xh) << 3)];       \
        _Pragma("unroll") for (int j = 0; j < 4; ++j)                          \
            _Pragma("unroll") for (int kk = 0; kk < 2; ++kk)                   \
                bfr[j][kk] = *(const bf16x8*)&Ws[buf][(j * 16 + l16) * 64 +    \
                                             (((kk * 4 + quad) ^ xh) << 3)];   \
        _Pragma("unroll") for (int kk = 0; kk < 2; ++kk)                       \
            _Pragma("unroll") for (int j = 0; j < 4; ++j)                      \
                acc[j] = __builtin_amdgcn_mfma_f32_16x16x32_bf16(              \
                    af[kk], bfr[j][kk], acc[j], 0, 0, 0);                      \
        asm volatile("s_waitcnt lgkmcnt(0)" ::: "memory");                     \
        __builtin_amdgcn_s_barrier();                                          \
    }

// ===========================================================================
// 128x64-tile bf16 MFMA GEMM, BK=64, same XOR swizzle, 2-phase dbuf +
// counted vmcnt(6). Wave w owns rows w*32..+31 (2 m-subtiles) x all 64 cols:
// 16 MFMA vs 12 ds_read + 6 staging per k-tile. LDS 48KB -> 3 blocks/CU.
// [r15: qxt+kv conversion = -4.6us; r16: gemm_out at 2 blocks/CU also fine.]
// ===========================================================================
#define GEMM128x64P_PROLOG(Aptr, Wptr, Kdim)                                   \
    __shared__ unsigned short As[2][128 * 64];                                 \
    __shared__ unsigned short Ws[2][64 * 64];                                  \
    const int tid = threadIdx.x;                                               \
    const int w = tid >> 6, lane = tid & 63;                                   \
    const int l16 = lane & 15, quad = lane >> 4;                               \
    const int srow = lane >> 3;                                                \
    const int sw8 = ((lane & 7) ^ srow) << 3;                                  \
    const unsigned short* Ag = (Aptr) + (size_t)(m0 + w * 32 + srow) * (Kdim) + sw8; \
    const unsigned short* Wg = (Wptr) + (size_t)(n0 + w * 16 + srow) * (Kdim) + sw8; \
    const int xh = (l16 & 7);                                                  \
    f32x4 acc[2][4];                                                           \
    _Pragma("unroll") for (int mi = 0; mi < 2; ++mi)                           \
        _Pragma("unroll") for (int j = 0; j < 4; ++j)                          \
            acc[mi][j] = (f32x4){0.f, 0.f, 0.f, 0.f};                          \
    _Pragma("unroll") for (int seg = 0; seg < 4; ++seg)                        \
        gl_lds16(Ag + (size_t)(seg * 8) * (Kdim), &As[0][(w * 32 + seg * 8) * 64]); \
    _Pragma("unroll") for (int seg = 0; seg < 2; ++seg)                        \
        gl_lds16(Wg + (size_t)(seg * 8) * (Kdim), &Ws[0][(w * 16 + seg * 8) * 64]); \
    for (int k0 = 0, buf = 0; k0 < (Kdim); k0 += 64, buf ^= 1) {               \
        if (k0 + 64 < (Kdim)) {                                                \
            _Pragma("unroll") for (int seg = 0; seg < 4; ++seg)                \
                gl_lds16(Ag + (size_t)(seg * 8) * (Kdim) + k0 + 64,            \
                         &As[buf ^ 1][(w * 32 + seg * 8) * 64]);               \
            _Pragma("unroll") for (int seg = 0; seg < 2; ++seg)                \
                gl_lds16(Wg + (size_t)(seg * 8) * (Kdim) + k0 + 64,            \
                         &Ws[buf ^ 1][(w * 16 + seg * 8) * 64]);               \
            asm volatile("s_waitcnt vmcnt(6)" ::: "memory");                   \
        } else {                                                               \
            asm volatile("s_waitcnt vmcnt(0)" ::: "memory");                   \
        }                                                                      \
        __builtin_amdgcn_s_barrier();                                          \
        bf16x8 af[2][2], bfr[4][2];                                            \
        _Pragma("unroll") for (int mi = 0; mi < 2; ++mi)                       \
            _Pragma("unroll") for (int kk = 0; kk < 2; ++kk)                   \
                af[mi][kk] = *(const bf16x8*)&As[buf][(w * 32 + mi * 16 + l16) * 64 + \
                                             (((kk * 4 + quad) ^ xh) << 3)];   \
        _Pragma("unroll") for (int j = 0; j < 4; ++j)                          \
            _Pragma("unroll") for (int kk = 0; kk < 2; ++kk)                   \
                bfr[j][kk] = *(const bf16x8*)&Ws[buf][(j * 16 + l16) * 64 +    \
                                             (((kk * 4 + quad) ^ xh) << 3)];   \
        _Pragma("unroll") for (int kk = 0; kk < 2; ++kk)                       \
            _Pragma("unroll") for (int mi = 0; mi < 2; ++mi)                   \
                _Pragma("unroll") for (int j = 0; j < 4; ++j)                  \
                    acc[mi][j] = __builtin_amdgcn_mfma_f32_16x16x32_bf16(      \
                        af[mi][kk], bfr[j][kk], acc[mi][j], 0, 0, 0);          \
        asm volatile("s_waitcnt lgkmcnt(0)" ::: "memory");                     \
        __builtin_amdgcn_s_barrier();                                          \
    }

// ---------------------------------------------------------------------------
// Combined Q-projection (+RoPE+scale) and XT (softplus) GEMM. grid (32, 24).
// ---------------------------------------------------------------------------
__global__ __launch_bounds__(256, 3) void gemm_qxt(
    const unsigned short* __restrict__ A, const unsigned short* __restrict__ Wq,
    const unsigned short* __restrict__ Wkvl,
    const float* __restrict__ b_q, const float* __restrict__ b_kvl,
    const float* __restrict__ ts_scale, const float* __restrict__ ts_shift,
    const float2* __restrict__ tab,
    unsigned short* __restrict__ qh, unsigned short* __restrict__ xt)
{
    const int m0 = blockIdx.x * 128;
    const bool is_q = (blockIdx.y < 16);
    const int n0 = is_q ? blockIdx.y * 64 : (blockIdx.y - 16) * 64;
    const unsigned short* W = is_q ? Wq : Wkvl;

    GEMM128x64P_PROLOG(A, W, D_MOD)

    if (is_q) {
#pragma unroll
        for (int j = 0; j < 4; ++j) {
            const int col = n0 + j * 16 + l16;
            const int h = col >> 6, hd = col & 63;
            const float bv = b_q[col];
            const float bvp = b_q[col ^ 32];
            const float sgn = (hd < 32) ? -1.f : 1.f;
#pragma unroll
            for (int mi = 0; mi < 2; ++mi) {
#pragma unroll
                for (int reg = 0; reg < 4; ++reg) {
                    const int row = m0 + w * 32 + mi * 16 + quad * 4 + reg;
                    const int b = row >> 11, t = row & (T_SEQ - 1);
                    const float2 cssn = tab[t * 32 + (hd & 31)];
                    const float v  = acc[mi][j][reg] + bv;
                    const float vp = acc[mi][j ^ 2][reg] + bvp;
                    const float r = (v * cssn.x + sgn * vp * cssn.y) * SCALE_Q;
                    qh[(((size_t)b * NH + h) * T_SEQ + t) * HDIM + hd] = f2bf(r);
                }
            }
        }
    } else {
#pragma unroll
        for (int j = 0; j < 4; ++j) {
            const int col = n0 + j * 16 + l16;
            const float bv = b_kvl[col];
            const float sp_s = log1pf(expf(ts_scale[col]));
            const float sp_t = ts_shift[col];
#pragma unroll
            for (int mi = 0; mi < 2; ++mi) {
#pragma unroll
                for (int reg = 0; reg < 4; ++reg) {
                    const int row = m0 + w * 32 + mi * 16 + quad * 4 + reg;
                    const float val = (acc[mi][j][reg] + bv) * sp_s + sp_t;
                    xt[(size_t)row * DL + col] = f2bf(val);
                }
            }
        }
    }
}

// ---------------------------------------------------------------------------
// W_comb = W_fkv @ W_exp  [2048x512]@[512x256] -> [2048x256] bf16.
// r18 fusion: kv = (C_ln @ W_exp^T) @ W_fkv^T = C_ln @ W_comb^T. grid (32,4).
// ---------------------------------------------------------------------------
__global__ __launch_bounds__(256) void gemm_wcomb(
    const unsigned short* __restrict__ A,    // wfkvh [2048][512] (e, l)
    const unsigned short* __restrict__ W,    // wexpTh [256][512] (c, l)
    unsigned short* __restrict__ wcomb)      // [2048][256] (e, c)
{
    const int m0 = blockIdx.x * 64, n0 = blockIdx.y * 64;

    GEMM64P_PROLOG(A, W, DL)

#pragma unroll
    for (int j = 0; j < 4; ++j) {
        const int col = n0 + j * 16 + l16;
#pragma unroll
        for (int reg = 0; reg < 4; ++reg) {
            const int row = m0 + w * 16 + quad * 4 + reg;
            wcomb[(size_t)row * DC + col] = f2bf(acc[j][reg]);
        }
    }
}

// ---------------------------------------------------------------------------
// KV decompress GEMM (fused W_comb path, K=256) with fused K-RoPE and
// V-transpose. grid (32, 32). A = cbh [4096][256], W = wcombh [2048][256].
// ---------------------------------------------------------------------------
__global__ __launch_bounds__(256, 3) void gemm_kv(
    const unsigned short* __restrict__ A, const unsigned short* __restrict__ W,
    const float* __restrict__ bias, const float2* __restrict__ tab,
    unsigned short* __restrict__ kh, unsigned short* __restrict__ vth)
{
    const int m0 = blockIdx.x * 128, n0 = blockIdx.y * 64;

    GEMM128x64P_PROLOG(A, W, DC)

    if (n0 < 1024) {
        // K path: bias + RoPE -> kh [B*H, T, 64]
#pragma unroll
        for (int j = 0; j < 4; ++j) {
            const int col = n0 + j * 16 + l16;
            const int h = (col >> 6) & 15, hd = col & 63;
            const float bv = bias[col];
            const float bvp = bias[col ^ 32];
            const float sgn = (hd < 32) ? -1.f : 1.f;
#pragma unroll
            for (int mi = 0; mi < 2; ++mi) {
#pragma unroll
                for (int reg = 0; reg < 4; ++reg) {
                    const int row = m0 + w * 32 + mi * 16 + quad * 4 + reg;
                    const int b = row >> 11, t = row & (T_SEQ - 1);
                    const float2 cssn = tab[t * 32 + (hd & 31)];
                    const float v  = acc[mi][j][reg] + bv;
                    const float vp = acc[mi][j ^ 2][reg] + bvp;
                    const float r = v * cssn.x + sgn * vp * cssn.y;
                    kh[(((size_t)b * NH + h) * T_SEQ + t) * HDIM + hd] = f2bf(r);
                }
            }
        }
    } else {
        // V path: bias, transpose -> vth [B*H, 64, T] (packed 8B stores).
#pragma unroll
        for (int j = 0; j < 4; ++j) {
            const int col = n0 + j * 16 + l16;
            const int cv = col - 1024;
            const int h = cv >> 6, hd = cv & 63;
            const float bv = bias[col];
#pragma unroll
            for (int mi = 0; mi < 2; ++mi) {
                unsigned short hv[4];
                const int r0 = m0 + w * 32 + mi * 16 + quad * 4;
                const int b = r0 >> 11, t0 = r0 & (T_SEQ - 1);
#pragma unroll
                for (int reg = 0; reg < 4; ++reg)
                    hv[reg] = f2bf(acc[mi][j][reg] + bv);
                *(uint2*)&vth[(((size_t)b * NH + h) * HDIM + hd) * T_SEQ + t0] =
                    *(uint2*)hv;
            }
        }
    }
}

// ---------------------------------------------------------------------------
// Output GEMM: out[M,1024] fp32. grid (32, 16), 128x64 pipelined tile.
// ---------------------------------------------------------------------------
__global__ __launch_bounds__(256, 3) void gemm_out(
    const unsigned short* __restrict__ A, const unsigned short* __restrict__ W,
    const float* __restrict__ bias, float* __restrict__ C)
{
    const int m0 = blockIdx.x * 128, n0 = blockIdx.y * 64;

    GEMM128x64P_PROLOG(A, W, D_MOD)

#pragma unroll
    for (int j = 0; j < 4; ++j) {
        const int col = n0 + j * 16 + l16;
        const float bv = bias[col];
#pragma unroll
        for (int mi = 0; mi < 2; ++mi) {
#pragma unroll
            for (int reg = 0; reg < 4; ++reg) {
                const int row = m0 + w * 32 + mi * 16 + quad * 4 + reg;
                C[(size_t)row * D_MOD + col] = acc[mi][j][reg] + bv;
            }
        }
    }
}

// ---------------------------------------------------------------------------
// C-GEMM with fused LayerNorm. Block = 16 rows x 256 cols, grid 256 =
// 1 block/CU, 2-phase double-buffered K-loop (r16).
// ---------------------------------------------------------------------------
__global__ __launch_bounds__(256) void gemm_c_ln(
    const unsigned short* __restrict__ A, const unsigned short* __restrict__ W,
    const float* __restrict__ g, const float* __restrict__ bta,
    unsigned short* __restrict__ outb)
{
    __shared__ unsigned short As[2][16 * 32];
    __shared__ unsigned short Ws[2][256 * 32];
    __shared__ float redS[4][16];
    __shared__ float redQ[4][16];

    const int tid = threadIdx.x;
    const int w = tid >> 6, lane = tid & 63;
    const int l16 = lane & 15, quad = lane >> 4;
    const int m0 = blockIdx.x * 16;

    const int srow = lane >> 2, scol = (lane & 3) << 3;
    const unsigned short* Ag = A + (size_t)(m0 + srow) * DL + scol;
    const unsigned short* Wg = W + (size_t)(w * 64 + srow) * DL + scol;

    f32x4 acc[4];
#pragma unroll
    for (int j = 0; j < 4; ++j) acc[j] = (f32x4){0.f, 0.f, 0.f, 0.f};

    if (w == 0) gl_lds16(Ag, &As[0][0]);
#pragma unroll
    for (int c = 0; c < 4; ++c)
        gl_lds16(Wg + (size_t)(c * 16) * DL, &Ws[0][(w * 64 + c * 16) * 32]);

    for (int k0 = 0, buf = 0; k0 < DL; k0 += 32, buf ^= 1) {
        if (k0 + 32 < DL) {
            if (w == 0) gl_lds16(Ag + k0 + 32, &As[buf ^ 1][0]);
#pragma unroll
            for (int c = 0; c < 4; ++c)
                gl_lds16(Wg + (size_t)(c * 16) * DL + k0 + 32,
                         &Ws[buf ^ 1][(w * 64 + c * 16) * 32]);
            if (w == 0) {
                asm volatile("s_waitcnt vmcnt(5)" ::: "memory");
            } else {
                asm volatile("s_waitcnt vmcnt(4)" ::: "memory");
            }
        } else {
            asm volatile("s_waitcnt vmcnt(0)" ::: "memory");
        }
        __builtin_amdgcn_s_barrier();

        const bf16x8 af = *(const bf16x8*)&As[buf][l16 * 32 + quad * 8];
        bf16x8 bfr[4];
#pragma unroll
        for (int j = 0; j < 4; ++j)
            bfr[j] = *(const bf16x8*)&Ws[buf][(w * 64 + j * 16 + l16) * 32 + quad * 8];
#pragma unroll
        for (int j = 0; j < 4; ++j)
            acc[j] = __builtin_amdgcn_mfma_f32_16x16x32_bf16(af, bfr[j], acc[j], 0, 0, 0);

        asm volatile("s_waitcnt lgkmcnt(0)" ::: "memory");
        __builtin_amdgcn_s_barrier();
    }

    float s[4], q2[4];
#pragma unroll
    for (int reg = 0; reg < 4; ++reg) {
        float sv = (acc[0][reg] + acc[1][reg]) + (acc[2][reg] + acc[3][reg]);
        float qv = (acc[0][reg] * acc[0][reg] + acc[1][reg] * acc[1][reg]) +
                   (acc[2][reg] * acc[2][reg] + acc[3][reg] * acc[3][reg]);
#pragma unroll
        for (int off = 1; off < 16; off <<= 1) {
            sv += __shfl_xor(sv, off);
            qv += __shfl_xor(qv, off);
        }
        s[reg] = sv; q2[reg] = qv;
    }
    if (l16 == 0) {
#pragma unroll
        for (int reg = 0; reg < 4; ++reg) {
            redS[w][quad * 4 + reg] = s[reg];
            redQ[w][quad * 4 + reg] = q2[reg];
        }
    }
    __syncthreads();

#pragma unroll
    for (int reg = 0; reg < 4; ++reg) {
        const int r = quad * 4 + reg;
        const float sum = (redS[0][r] + redS[1][r]) + (redS[2][r] + redS[3][r]);
        const float sq  = (redQ[0][r] + redQ[1][r]) + (redQ[2][r] + redQ[3][r]);
        const float mu  = sum * (1.0f / DC);
        const float var = sq * (1.0f / DC) - mu * mu;
        const float rstd = rsqrtf(var + 1e-5f);
#pragma unroll
        for (int j = 0; j < 4; ++j) {
            const int col = w * 64 + j * 16 + l16;
            const float val = (acc[j][reg] - mu) * rstd * g[col] + bta[col];
            outb[(size_t)(m0 + r) * DC + col] = f2bf(val);
        }
    }
}

// ---------------------------------------------------------------------------
// MFMA flash attention (round-10 body + round-13 balanced block remap).
// With 1024 blocks at exactly 4 blocks/CU ALL blocks are resident at t=0,
// so ordering is irrelevant; what matters is which 4 blocks CO-LOCATE on a
// CU. MI355X dispatch round-robins XCDs (b%8) then CUs -> co-located blocks
// are b = b0 (mod 256). Old j=31-(b>>5) gave per-CU k-tile sums 52..80
// (1.21x tail, visible as 28% occupancy). New mapping: bh=b&31, gq=(b>>5)&7,
// r=b>>8; j in {2gq, 31-2gq, 2gq+1, 30-2gq} by r -> per-CU sum = 66 exactly,
// bijective over (bh,j), and co-located blocks share the head's K/V (L1
// reuse). Body unchanged: counted-wait barrier, stride-64 XOR-swizzled
// K/V/P LDS (conflicts=0, 40960 B = 4 blocks/CU), T14 reg-prefetch + dbuf,
// setprio.
// [r20: vf hoist spilled under launch_bounds(256,4) — keep vf after softmax.]
// [r19: counted barrier neutral. r14: no-LDS regressed 3x. r12: 32 q-rows
//  regressed — keep 64-row q-tiles + 1024 blocks.]
// ---------------------------------------------------------------------------
__global__ __launch_bounds__(256, 4) void flash_mfma(
    const unsigned short* __restrict__ q, const unsigned short* __restrict__ k,
    const unsigned short* __restrict__ vt, unsigned short* __restrict__ o)
{
    __shared__ unsigned short Ks[2][64 * 64];
    __shared__ unsigned short Vs[2][64 * 64];
    __shared__ unsigned short Ps[64 * 64];

    const int bh = blockIdx.x & 31;
    const int gq = (blockIdx.x >> 5) & 7;
    const int rr = blockIdx.x >> 8;
    const int j  = (rr == 0) ? (2 * gq)
                 : (rr == 1) ? (31 - 2 * gq)
                 : (rr == 2) ? (2 * gq + 1)
                             : (30 - 2 * gq);
    const int q0 = j * 64;
    const int tid = threadIdx.x;
    const int w = tid >> 6, lane = tid & 63;
    const int l16 = lane & 15, quad = lane >> 4;
    const int rbase = q0 + w * 16;
    const int xh = l16 & 7;

    bf16x8 qf[2];
#pragma unroll
    for (int kk = 0; kk < 2; ++kk)
        qf[kk] = *(const bf16x8*)(q + ((size_t)bh * T_SEQ + rbase + l16) * HDIM + kk * 32 + quad * 8);

    f32x4 of[4];
    float lrow[4];
#pragma unroll
    for (int dt = 0; dt < 4; ++dt) of[dt] = (f32x4){0.f, 0.f, 0.f, 0.f};
#pragma unroll
    for (int r = 0; r < 4; ++r) lrow[r] = 0.f;

    const int ldr = tid >> 2;
    const int ldc = (tid & 3) * 16;
    // Swizzled store offsets for this lane's two b128 stores (groups g, g+1).
    const int sg0 = (((ldc >> 3) + 0) ^ (ldr & 7)) << 3;
    const int sg1 = (((ldc >> 3) + 1) ^ (ldr & 7)) << 3;
    const unsigned short* kgb = k + ((size_t)bh * T_SEQ + ldr) * HDIM + ldc;
    const unsigned short* vgb = vt + ((size_t)bh * HDIM + ldr) * T_SEQ + ldc;

    // Prefetch tile 0 into registers (T14 issue-early).
    bf16x8 kr0 = *(const bf16x8*)kgb;
    bf16x8 kr1 = *(const bf16x8*)(kgb + 8);
    bf16x8 vr0 = *(const bf16x8*)vgb;
    bf16x8 vr1 = *(const bf16x8*)(vgb + 8);

    const int kend = (j + 1) * 64;
    int buf = 0;
    for (int k0 = 0; k0 < kend; k0 += 64, buf ^= 1) {
        // Write staged regs to LDS (write-late half of T14), swizzled.
        *(bf16x8*)&Ks[buf][ldr * 64 + sg0] = kr0;
        *(bf16x8*)&Ks[buf][ldr * 64 + sg1] = kr1;
        *(bf16x8*)&Vs[buf][ldr * 64 + sg0] = vr0;
        *(bf16x8*)&Vs[buf][ldr * 64 + sg1] = vr1;
        // Issue next-tile loads; they stay in flight ACROSS the barrier.
        if (k0 + 64 < kend) {
            const unsigned short* kg = kgb + (size_t)(k0 + 64) * HDIM;
            const unsigned short* vg = vgb + (k0 + 64);
            kr0 = *(const bf16x8*)kg;
            kr1 = *(const bf16x8*)(kg + 8);
            vr0 = *(const bf16x8*)vg;
            vr1 = *(const bf16x8*)(vg + 8);
        }
        // Counted-wait barrier: ds ops drained, global loads NOT (r19).
        asm volatile("s_waitcnt lgkmcnt(0)" ::: "memory");
        __builtin_amdgcn_s_barrier();

        bf16x8 kf[4][2];
#pragma unroll
        for (int nt = 0; nt < 4; ++nt)
#pragma unroll
            for (int kk = 0; kk < 2; ++kk)
                kf[nt][kk] = *(const bf16x8*)&Ks[buf][(nt * 16 + l16) * 64 +
                                                     (((kk * 4 + quad) ^ xh) << 3)];

        f32x4 sf[4];
        __builtin_amdgcn_s_setprio(1);
#pragma unroll
        for (int nt = 0; nt < 4; ++nt) {
            sf[nt] = (f32x4){0.f, 0.f, 0.f, 0.f};
#pragma unroll
            for (int kk = 0; kk < 2; ++kk)
                sf[nt] = __builtin_amdgcn_mfma_f32_16x16x32_bf16(qf[kk], kf[nt][kk], sf[nt], 0, 0, 0);
        }
        __builtin_amdgcn_s_setprio(0);

        const bool need_mask = (k0 + 63) > rbase;
#pragma unroll
        for (int reg = 0; reg < 4; ++reg) {
            float a0 = sf[0][reg], a1 = sf[1][reg], a2 = sf[2][reg], a3 = sf[3][reg];
            if (need_mask) {
                const int tq = rbase + quad * 4 + reg;
                if (k0 +      l16 > tq) a0 = -1e30f;
                if (k0 + 16 + l16 > tq) a1 = -1e30f;
                if (k0 + 32 + l16 > tq) a2 = -1e30f;
                if (k0 + 48 + l16 > tq) a3 = -1e30f;
            }
            union { float f; unsigned u; } u0, u1, u2, u3;
            u0.f = exp2f(a0); u1.f = exp2f(a1);
            u2.f = exp2f(a2); u3.f = exp2f(a3);
            // P[prow][col=nt*16+l16] -> swizzled: prow*64 + (g^(prow&7))*8 + (l16&7),
            // g = nt*2 + (l16>>3).
            const int prow = w * 16 + quad * 4 + reg;
            const int pr7 = prow & 7;
            const int pb = prow * 64 + (l16 & 7);
            const int g0 = l16 >> 3;
            Ps[pb + (((0 + g0) ^ pr7) << 3)] = (unsigned short)(u0.u >> 16);
            Ps[pb + (((2 + g0) ^ pr7) << 3)] = (unsigned short)(u1.u >> 16);
            Ps[pb + (((4 + g0) ^ pr7) << 3)] = (unsigned short)(u2.u >> 16);
            Ps[pb + (((6 + g0) ^ pr7) << 3)] = (unsigned short)(u3.u >> 16);
            u0.u &= 0xffff0000u; u1.u &= 0xffff0000u;
            u2.u &= 0xffff0000u; u3.u &= 0xffff0000u;
            lrow[reg] += (u0.f + u1.f) + (u2.f + u3.f);
        }

        bf16x8 vf[4][2];
#pragma unroll
        for (int dt = 0; dt < 4; ++dt)
#pragma unroll
            for (int kk = 0; kk < 2; ++kk)
                vf[dt][kk] = *(const bf16x8*)&Vs[buf][(dt * 16 + l16) * 64 +
                                                     (((kk * 4 + quad) ^ xh) << 3)];

        bf16x8 pf[2];
#pragma unroll
        for (int kk = 0; kk < 2; ++kk)
            pf[kk] = *(const bf16x8*)&Ps[(w * 16 + l16) * 64 +
                                         (((kk * 4 + quad) ^ xh) << 3)];
        __builtin_amdgcn_s_setprio(1);
#pragma unroll
        for (int dt = 0; dt < 4; ++dt)
#pragma unroll
            for (int kk = 0; kk < 2; ++kk)
                of[dt] = __builtin_amdgcn_mfma_f32_16x16x32_bf16(pf[kk], vf[dt][kk], of[dt], 0, 0, 0);
        __builtin_amdgcn_s_setprio(0);
    }

    const int b = bh >> 4, h = bh & 15;
#pragma unroll
    for (int reg = 0; reg < 4; ++reg) {
        float l = lrow[reg];
        l += __shfl_xor(l, 1);
        l += __shfl_xor(l, 2);
        l += __shfl_xor(l, 4);
        l += __shfl_xor(l, 8);
        const float inv = 1.0f / l;
        const int t = rbase + quad * 4 + reg;
#pragma unroll
        for (int dt = 0; dt < 4; ++dt)
            o[((size_t)b * T_SEQ + t) * (NH * HDIM) + h * HDIM + dt * 16 + l16] =
                f2bf(of[dt][reg] * inv);
    }
}

// ---------------------------------------------------------------------------
extern "C" void kernel_launch(void* const* d_in, const int* in_sizes, int n_in,
                              void* d_out, int out_size, void* d_ws, size_t ws_size,
                              hipStream_t stream)
{
    (void)in_sizes; (void)n_in; (void)out_size; (void)ws_size;

    const float* x        = (const float*)d_in[0];
    const float* W_q      = (const float*)d_in[1];
    const float* b_q      = (const float*)d_in[2];
    const float* W_kvl    = (const float*)d_in[3];
    const float* b_kvl    = (const float*)d_in[4];
    const float* ts_scale = (const float*)d_in[5];
    const float* ts_shift = (const float*)d_in[6];
    const float* W_comp   = (const float*)d_in[7];
    const float* W_exp    = (const float*)d_in[8];
    const float* ln_g     = (const float*)d_in[9];
    const float* ln_b     = (const float*)d_in[10];
    const float* W_fkv    = (const float*)d_in[11];
    const float* b_fkv    = (const float*)d_in[12];
    const float* W_out    = (const float*)d_in[13];
    const float* b_out    = (const float*)d_in[14];
    float* out = (float*)d_out;

    char* p = (char*)d_ws;
    unsigned short* xb     = (unsigned short*)p;             p += 8  * 1024 * 1024;
    unsigned short* wqh    = (unsigned short*)p;             p += 2  * 1024 * 1024;
    unsigned short* wkvlh  = (unsigned short*)p;             p += 1  * 1024 * 1024;
    unsigned short* wcomph = (unsigned short*)p;             p += 256 * 1024;
    unsigned short* wexpTh = (unsigned short*)p;             p += 256 * 1024;
    unsigned short* wfkvh  = (unsigned short*)p;             p += 2  * 1024 * 1024;
    unsigned short* wouth  = (unsigned short*)p;             p += 2  * 1024 * 1024;
    unsigned short* qh     = (unsigned short*)p;             p += 8  * 1024 * 1024;
    unsigned short* kh     = (unsigned short*)p;             p += 8  * 1024 * 1024;
    unsigned short* vth    = (unsigned short*)p;             p += 8  * 1024 * 1024;
    unsigned short* xt     = (unsigned short*)p;             p += 4  * 1024 * 1024;
    unsigned short* cbh    = (unsigned short*)p;             p += 2  * 1024 * 1024;
    unsigned short* wcombh = (unsigned short*)p;             p += 4  * 1024 * 1024;
    unsigned short* ob     = (unsigned short*)p;             p += 8  * 1024 * 1024;
    float2*         tab    = (float2*)p;                     p += 512 * 1024;

    const dim3 blk(256);

    cvt_bf16<<<1024, blk, 0, stream>>>(x, W_q, W_kvl, W_comp, W_exp, W_fkv, W_out,
                                       xb, wqh, wkvlh, wcomph, wexpTh, wfkvh, wouth,
                                       tab);

    gemm_wcomb<<<dim3(32, 4), blk, 0, stream>>>(
        wfkvh, wexpTh, wcombh);

    gemm_qxt<<<dim3(32, 24), blk, 0, stream>>>(
        xb, wqh, wkvlh, b_q, b_kvl, ts_scale, ts_shift, tab, qh, xt);

    gemm_c_ln<<<256, blk, 0, stream>>>(
        xt, wcomph, ln_g, ln_b, cbh);

    gemm_kv<<<dim3(32, 32), blk, 0, stream>>>(
        cbh, wcombh, b_fkv, tab, kh, vth);

    flash_mfma<<<1024, blk, 0, stream>>>(qh, kh, vth, ob);

    gemm_out<<<dim3(32, 16), blk, 0, stream>>>(
        ob, wouth, b_out, out);
}

// Round 14
// 206.856 us; speedup vs baseline: 1.0331x; 1.0331x over previous
//
#include <hip/hip_runtime.h>
#include <math.h>

#define B_SZ   2
#define T_SEQ  2048
#define NH     16
#define HDIM   64
#define D_MOD  1024
#define DL     512
#define DC     256
#define MROWS  4096   // B*T

typedef __attribute__((ext_vector_type(8))) short bf16x8;
typedef __attribute__((ext_vector_type(4))) float f32x4;

#define SCALE_Q 0.18033688011112042f   // (1/sqrt(64)) * log2(e)

static __device__ __forceinline__ unsigned short f2bf(float f) {
    union { float f; unsigned u; } v; v.f = f;
    unsigned r = v.u + 0x7fffu + ((v.u >> 16) & 1u);   // RNE
    return (unsigned short)(r >> 16);
}

// async global->LDS, 16B per lane; lds base wave-uniform, lane i -> base+i*16.
static __device__ __forceinline__ void gl_lds16(const unsigned short* g,
                                                unsigned short* l) {
    __builtin_amdgcn_global_load_lds(
        (const __attribute__((address_space(1))) unsigned int*)g,
        (__attribute__((address_space(3))) unsigned int*)l, 16, 0, 0);
}

// ---------------------------------------------------------------------------
// Convert x + weights fp32 -> bf16 (W_exp transposed: its only consumer is
// the wcomb GEMM which needs [c][l]), and build RoPE table [T,32] (cos,sin).
// ---------------------------------------------------------------------------
__global__ __launch_bounds__(256) void cvt_bf16(
    const float* __restrict__ x,  const float* __restrict__ wq,
    const float* __restrict__ wkvl, const float* __restrict__ wcomp,
    const float* __restrict__ wexp, const float* __restrict__ wfkv,
    const float* __restrict__ wout,
    unsigned short* __restrict__ xb,  unsigned short* __restrict__ wqh,
    unsigned short* __restrict__ wkvlh, unsigned short* __restrict__ wcomph,
    unsigned short* __restrict__ wexpTh, unsigned short* __restrict__ wfkvh,
    unsigned short* __restrict__ wouth, float2* __restrict__ rope_tab)
{
    const int g = blockIdx.x * 256 + threadIdx.x;
    const int stride = gridDim.x * 256;
#define CVT_SEG(src, dst, n4)                                              \
    for (int i = g; i < (n4); i += stride) {                               \
        float4 v = ((const float4*)(src))[i];                              \
        unsigned short h[4] = {f2bf(v.x), f2bf(v.y), f2bf(v.z), f2bf(v.w)};\
        *(uint2*)((dst) + (size_t)i * 4) = *(uint2*)h;                     \
    }
    CVT_SEG(x, xb, 1048576)
    CVT_SEG(wq, wqh, 262144)
    CVT_SEG(wkvl, wkvlh, 131072)
    CVT_SEG(wcomp, wcomph, 32768)
    CVT_SEG(wfkv, wfkvh, 262144)
    CVT_SEG(wout, wouth, 262144)
#undef CVT_SEG
    // W_exp [512(l)][256(c)] fp32 -> wexpTh [256(c)][512(l)] bf16.
    // i = c*128 + l4; writes coalesced (8B), reads strided (L2-small tensor).
    for (int i = g; i < 32768; i += stride) {
        const int c = i >> 7, l4 = (i & 127) << 2;
        unsigned short h[4];
#pragma unroll
        for (int r = 0; r < 4; ++r)
            h[r] = f2bf(wexp[(size_t)(l4 + r) * DC + c]);
        *(uint2*)(wexpTh + (size_t)c * DL + l4) = *(uint2*)h;
    }
    for (int i = g; i < T_SEQ * 32; i += stride) {
        const int t = i >> 5, fi = i & 31;
        const float inv = __expf((float)fi * (-9.210340371976184f / 32.0f));
        float sn, cs; sincosf((float)t * inv, &sn, &cs);
        rope_tab[i] = make_float2(cs, sn);
    }
}

// ===========================================================================
// 64x64-tile bf16 MFMA GEMM, BK=64, XOR-swizzled LDS, 2-phase dbuf pipeline.
// [r13: neutral vs 2-barrier — kept. r10: 128^2 regressed at 1-2 blocks/CU.]
// ===========================================================================
#define GEMM64P_PROLOG(Aptr, Wptr, Kdim)                                       \
    __shared__ unsigned short As[2][64 * 64];                                  \
    __shared__ unsigned short Ws[2][64 * 64];                                  \
    const int tid = threadIdx.x;                                               \
    const int w = tid >> 6, lane = tid & 63;                                   \
    const int l16 = lane & 15, quad = lane >> 4;                               \
    const int sw8 = ((lane & 7) ^ ((lane >> 3) & 7)) << 3;                     \
    const int srow = lane >> 3;                                                \
    const unsigned short* Ag0 = (Aptr) + (size_t)(m0 + w * 16 + srow) * (Kdim) + sw8;      \
    const unsigned short* Ag1 = Ag0 + (size_t)8 * (Kdim);                      \
    const unsigned short* Wg0 = (Wptr) + (size_t)(n0 + w * 16 + srow) * (Kdim) + sw8;      \
    const unsigned short* Wg1 = Wg0 + (size_t)8 * (Kdim);                      \
    const int aoff = (w * 16) * 64;                                            \
    const int xh = (l16 & 7);                                                  \
    f32x4 acc[4];                                                              \
    _Pragma("unroll") for (int j = 0; j < 4; ++j)                              \
        acc[j] = (f32x4){0.f, 0.f, 0.f, 0.f};                                  \
    gl_lds16(Ag0, &As[0][aoff]);                                               \
    gl_lds16(Ag1, &As[0][aoff + 512]);                                         \
    gl_lds16(Wg0, &Ws[0][aoff]);                                               \
    gl_lds16(Wg1, &Ws[0][aoff + 512]);                                         \
    for (int k0 = 0, buf = 0; k0 < (Kdim); k0 += 64, buf ^= 1) {               \
        if (k0 + 64 < (Kdim)) {                                                \
            gl_lds16(Ag0 + k0 + 64, &As[buf ^ 1][aoff]);                       \
            gl_lds16(Ag1 + k0 + 64, &As[buf ^ 1][aoff + 512]);                 \
            gl_lds16(Wg0 + k0 + 64, &Ws[buf ^ 1][aoff]);                       \
            gl_lds16(Wg1 + k0 + 64, &Ws[buf ^ 1][aoff + 512]);                 \
            asm volatile("s_waitcnt vmcnt(4)" ::: "memory");                   \
        } else {                                                               \
            asm volatile("s_waitcnt vmcnt(0)" ::: "memory");                   \
        }                                                                      \
        __builtin_amdgcn_s_barrier();                                          \
        bf16x8 af[2], bfr[4][2];                                               \
        _Pragma("unroll") for (int kk = 0; kk < 2; ++kk)                       \
            af[kk] = *(const bf16x8*)&As[buf][(w * 16 + l16) * 64 +            \
                                         (((kk * 4 + quad) ^ xh) << 3)];       \
        _Pragma("unroll") for (int j = 0; j < 4; ++j)                          \
            _Pragma("unroll") for (int kk = 0; kk < 2; ++kk)                   \
                bfr[j][kk] = *(const bf16x8*)&Ws[buf][(j * 16 + l16) * 64 +    \
                                             (((kk * 4 + quad) ^ xh) << 3)];   \
        _Pragma("unroll") for (int kk = 0; kk < 2; ++kk)                       \
            _Pragma("unroll") for (int j = 0; j < 4; ++j)                      \
                acc[j] = __builtin_amdgcn_mfma_f32_16x16x32_bf16(              \
                    af[kk], bfr[j][kk], acc[j], 0, 0, 0);                      \
        asm volatile("s_waitcnt lgkmcnt(0)" ::: "memory");                     \
        __builtin_amdgcn_s_barrier();                                          \
    }

// ===========================================================================
// 128x64-tile bf16 MFMA GEMM, BK=64, same XOR swizzle, 2-phase dbuf +
// counted vmcnt(6). Wave w owns rows w*32..+31 (2 m-subtiles) x all 64 cols:
// 16 MFMA vs 12 ds_read + 6 staging per k-tile. LDS 48KB -> 3 blocks/CU.
// [r15: qxt+kv conversion = -4.6us; r16: gemm_out at 2 blocks/CU also fine.]
// ===========================================================================
#define GEMM128x64P_PROLOG(Aptr, Wptr, Kdim)                                   \
    __shared__ unsigned short As[2][128 * 64];                                 \
    __shared__ unsigned short Ws[2][64 * 64];                                  \
    const int tid = threadIdx.x;                                               \
    const int w = tid >> 6, lane = tid & 63;                                   \
    const int l16 = lane & 15, quad = lane >> 4;                               \
    const int srow = lane >> 3;                                                \
    const int sw8 = ((lane & 7) ^ srow) << 3;                                  \
    const unsigned short* Ag = (Aptr) + (size_t)(m0 + w * 32 + srow) * (Kdim) + sw8; \
    const unsigned short* Wg = (Wptr) + (size_t)(n0 + w * 16 + srow) * (Kdim) + sw8; \
    const int xh = (l16 & 7);                                                  \
    f32x4 acc[2][4];                                                           \
    _Pragma("unroll") for (int mi = 0; mi < 2; ++mi)                           \
        _Pragma("unroll") for (int j = 0; j < 4; ++j)                          \
            acc[mi][j] = (f32x4){0.f, 0.f, 0.f, 0.f};                          \
    _Pragma("unroll") for (int seg = 0; seg < 4; ++seg)                        \
        gl_lds16(Ag + (size_t)(seg * 8) * (Kdim), &As[0][(w * 32 + seg * 8) * 64]); \
    _Pragma("unroll") for (int seg = 0; seg < 2; ++seg)                        \
        gl_lds16(Wg + (size_t)(seg * 8) * (Kdim), &Ws[0][(w * 16 + seg * 8) * 64]); \
    for (int k0 = 0, buf = 0; k0 < (Kdim); k0 += 64, buf ^= 1) {               \
        if (k0 + 64 < (Kdim)) {                                                \
            _Pragma("unroll") for (int seg = 0; seg < 4; ++seg)                \
                gl_lds16(Ag + (size_t)(seg * 8) * (Kdim) + k0 + 64,            \
                         &As[buf ^ 1][(w * 32 + seg * 8) * 64]);               \
            _Pragma("unroll") for (int seg = 0; seg < 2; ++seg)                \
                gl_lds16(Wg + (size_t)(seg * 8) * (Kdim) + k0 + 64,            \
                         &Ws[buf ^ 1][(w * 16 + seg * 8) * 64]);               \
            asm volatile("s_waitcnt vmcnt(6)" ::: "memory");                   \
        } else {                                                               \
            asm volatile("s_waitcnt vmcnt(0)" ::: "memory");                   \
        }                                                                      \
        __builtin_amdgcn_s_barrier();                                          \
        bf16x8 af[2][2], bfr[4][2];                                            \
        _Pragma("unroll") for (int mi = 0; mi < 2; ++mi)                       \
            _Pragma("unroll") for (int kk = 0; kk < 2; ++kk)                   \
                af[mi][kk] = *(const bf16x8*)&As[buf][(w * 32 + mi * 16 + l16) * 64 + \
                                             (((kk * 4 + quad) ^ xh) << 3)];   \
        _Pragma("unroll") for (int j = 0; j < 4; ++j)                          \
            _Pragma("unroll") for (int kk = 0; kk < 2; ++kk)                   \
                bfr[j][kk] = *(const bf16x8*)&Ws[buf][(j * 16 + l16) * 64 +    \
                                             (((kk * 4 + quad) ^ xh) << 3)];   \
        _Pragma("unroll") for (int kk = 0; kk < 2; ++kk)                       \
            _Pragma("unroll") for (int mi = 0; mi < 2; ++mi)                   \
                _Pragma("unroll") for (int j = 0; j < 4; ++j)                  \
                    acc[mi][j] = __builtin_amdgcn_mfma_f32_16x16x32_bf16(      \
                        af[mi][kk], bfr[j][kk], acc[mi][j], 0, 0, 0);          \
        asm volatile("s_waitcnt lgkmcnt(0)" ::: "memory");                     \
        __builtin_amdgcn_s_barrier();                                          \
    }

// ---------------------------------------------------------------------------
// Combined Q-projection (+RoPE+scale) and XT (softplus) GEMM. grid (32, 24).
// ---------------------------------------------------------------------------
__global__ __launch_bounds__(256, 3) void gemm_qxt(
    const unsigned short* __restrict__ A, const unsigned short* __restrict__ Wq,
    const unsigned short* __restrict__ Wkvl,
    const float* __restrict__ b_q, const float* __restrict__ b_kvl,
    const float* __restrict__ ts_scale, const float* __restrict__ ts_shift,
    const float2* __restrict__ tab,
    unsigned short* __restrict__ qh, unsigned short* __restrict__ xt)
{
    const int m0 = blockIdx.x * 128;
    const bool is_q = (blockIdx.y < 16);
    const int n0 = is_q ? blockIdx.y * 64 : (blockIdx.y - 16) * 64;
    const unsigned short* W = is_q ? Wq : Wkvl;

    GEMM128x64P_PROLOG(A, W, D_MOD)

    if (is_q) {
#pragma unroll
        for (int j = 0; j < 4; ++j) {
            const int col = n0 + j * 16 + l16;
            const int h = col >> 6, hd = col & 63;
            const float bv = b_q[col];
            const float bvp = b_q[col ^ 32];
            const float sgn = (hd < 32) ? -1.f : 1.f;
#pragma unroll
            for (int mi = 0; mi < 2; ++mi) {
#pragma unroll
                for (int reg = 0; reg < 4; ++reg) {
                    const int row = m0 + w * 32 + mi * 16 + quad * 4 + reg;
                    const int b = row >> 11, t = row & (T_SEQ - 1);
                    const float2 cssn = tab[t * 32 + (hd & 31)];
                    const float v  = acc[mi][j][reg] + bv;
                    const float vp = acc[mi][j ^ 2][reg] + bvp;
                    const float r = (v * cssn.x + sgn * vp * cssn.y) * SCALE_Q;
                    qh[(((size_t)b * NH + h) * T_SEQ + t) * HDIM + hd] = f2bf(r);
                }
            }
        }
    } else {
#pragma unroll
        for (int j = 0; j < 4; ++j) {
            const int col = n0 + j * 16 + l16;
            const float bv = b_kvl[col];
            const float sp_s = log1pf(expf(ts_scale[col]));
            const float sp_t = ts_shift[col];
#pragma unroll
            for (int mi = 0; mi < 2; ++mi) {
#pragma unroll
                for (int reg = 0; reg < 4; ++reg) {
                    const int row = m0 + w * 32 + mi * 16 + quad * 4 + reg;
                    const float val = (acc[mi][j][reg] + bv) * sp_s + sp_t;
                    xt[(size_t)row * DL + col] = f2bf(val);
                }
            }
        }
    }
}

// ---------------------------------------------------------------------------
// W_comb = W_fkv @ W_exp  [2048x512]@[512x256] -> [2048x256] bf16.
// r18 fusion: kv = (C_ln @ W_exp^T) @ W_fkv^T = C_ln @ W_comb^T. grid (32,4).
// ---------------------------------------------------------------------------
__global__ __launch_bounds__(256) void gemm_wcomb(
    const unsigned short* __restrict__ A,    // wfkvh [2048][512] (e, l)
    const unsigned short* __restrict__ W,    // wexpTh [256][512] (c, l)
    unsigned short* __restrict__ wcomb)      // [2048][256] (e, c)
{
    const int m0 = blockIdx.x * 64, n0 = blockIdx.y * 64;

    GEMM64P_PROLOG(A, W, DL)

#pragma unroll
    for (int j = 0; j < 4; ++j) {
        const int col = n0 + j * 16 + l16;
#pragma unroll
        for (int reg = 0; reg < 4; ++reg) {
            const int row = m0 + w * 16 + quad * 4 + reg;
            wcomb[(size_t)row * DC + col] = f2bf(acc[j][reg]);
        }
    }
}

// ---------------------------------------------------------------------------
// KV decompress GEMM (fused W_comb path, K=256) with fused K-RoPE and
// V-transpose. grid (32, 32). A = cbh [4096][256], W = wcombh [2048][256].
// ---------------------------------------------------------------------------
__global__ __launch_bounds__(256, 3) void gemm_kv(
    const unsigned short* __restrict__ A, const unsigned short* __restrict__ W,
    const float* __restrict__ bias, const float2* __restrict__ tab,
    unsigned short* __restrict__ kh, unsigned short* __restrict__ vth)
{
    const int m0 = blockIdx.x * 128, n0 = blockIdx.y * 64;

    GEMM128x64P_PROLOG(A, W, DC)

    if (n0 < 1024) {
        // K path: bias + RoPE -> kh [B*H, T, 64]
#pragma unroll
        for (int j = 0; j < 4; ++j) {
            const int col = n0 + j * 16 + l16;
            const int h = (col >> 6) & 15, hd = col & 63;
            const float bv = bias[col];
            const float bvp = bias[col ^ 32];
            const float sgn = (hd < 32) ? -1.f : 1.f;
#pragma unroll
            for (int mi = 0; mi < 2; ++mi) {
#pragma unroll
                for (int reg = 0; reg < 4; ++reg) {
                    const int row = m0 + w * 32 + mi * 16 + quad * 4 + reg;
                    const int b = row >> 11, t = row & (T_SEQ - 1);
                    const float2 cssn = tab[t * 32 + (hd & 31)];
                    const float v  = acc[mi][j][reg] + bv;
                    const float vp = acc[mi][j ^ 2][reg] + bvp;
                    const float r = v * cssn.x + sgn * vp * cssn.y;
                    kh[(((size_t)b * NH + h) * T_SEQ + t) * HDIM + hd] = f2bf(r);
                }
            }
        }
    } else {
        // V path: bias, transpose -> vth [B*H, 64, T] (packed 8B stores).
#pragma unroll
        for (int j = 0; j < 4; ++j) {
            const int col = n0 + j * 16 + l16;
            const int cv = col - 1024;
            const int h = cv >> 6, hd = cv & 63;
            const float bv = bias[col];
#pragma unroll
            for (int mi = 0; mi < 2; ++mi) {
                unsigned short hv[4];
                const int r0 = m0 + w * 32 + mi * 16 + quad * 4;
                const int b = r0 >> 11, t0 = r0 & (T_SEQ - 1);
#pragma unroll
                for (int reg = 0; reg < 4; ++reg)
                    hv[reg] = f2bf(acc[mi][j][reg] + bv);
                *(uint2*)&vth[(((size_t)b * NH + h) * HDIM + hd) * T_SEQ + t0] =
                    *(uint2*)hv;
            }
        }
    }
}

// ---------------------------------------------------------------------------
// Output GEMM: out[M,1024] fp32. grid (32, 16), 128x64 pipelined tile.
// ---------------------------------------------------------------------------
__global__ __launch_bounds__(256, 3) void gemm_out(
    const unsigned short* __restrict__ A, const unsigned short* __restrict__ W,
    const float* __restrict__ bias, float* __restrict__ C)
{
    const int m0 = blockIdx.x * 128, n0 = blockIdx.y * 64;

    GEMM128x64P_PROLOG(A, W, D_MOD)

#pragma unroll
    for (int j = 0; j < 4; ++j) {
        const int col = n0 + j * 16 + l16;
        const float bv = bias[col];
#pragma unroll
        for (int mi = 0; mi < 2; ++mi) {
#pragma unroll
            for (int reg = 0; reg < 4; ++reg) {
                const int row = m0 + w * 32 + mi * 16 + quad * 4 + reg;
                C[(size_t)row * D_MOD + col] = acc[mi][j][reg] + bv;
            }
        }
    }
}

// ---------------------------------------------------------------------------
// C-GEMM with fused LayerNorm. Block = 16 rows x 256 cols, grid 256 =
// 1 block/CU, 2-phase double-buffered K-loop (r16).
// ---------------------------------------------------------------------------
__global__ __launch_bounds__(256) void gemm_c_ln(
    const unsigned short* __restrict__ A, const unsigned short* __restrict__ W,
    const float* __restrict__ g, const float* __restrict__ bta,
    unsigned short* __restrict__ outb)
{
    __shared__ unsigned short As[2][16 * 32];
    __shared__ unsigned short Ws[2][256 * 32];
    __shared__ float redS[4][16];
    __shared__ float redQ[4][16];

    const int tid = threadIdx.x;
    const int w = tid >> 6, lane = tid & 63;
    const int l16 = lane & 15, quad = lane >> 4;
    const int m0 = blockIdx.x * 16;

    const int srow = lane >> 2, scol = (lane & 3) << 3;
    const unsigned short* Ag = A + (size_t)(m0 + srow) * DL + scol;
    const unsigned short* Wg = W + (size_t)(w * 64 + srow) * DL + scol;

    f32x4 acc[4];
#pragma unroll
    for (int j = 0; j < 4; ++j) acc[j] = (f32x4){0.f, 0.f, 0.f, 0.f};

    if (w == 0) gl_lds16(Ag, &As[0][0]);
#pragma unroll
    for (int c = 0; c < 4; ++c)
        gl_lds16(Wg + (size_t)(c * 16) * DL, &Ws[0][(w * 64 + c * 16) * 32]);

    for (int k0 = 0, buf = 0; k0 < DL; k0 += 32, buf ^= 1) {
        if (k0 + 32 < DL) {
            if (w == 0) gl_lds16(Ag + k0 + 32, &As[buf ^ 1][0]);
#pragma unroll
            for (int c = 0; c < 4; ++c)
                gl_lds16(Wg + (size_t)(c * 16) * DL + k0 + 32,
                         &Ws[buf ^ 1][(w * 64 + c * 16) * 32]);
            if (w == 0) {
                asm volatile("s_waitcnt vmcnt(5)" ::: "memory");
            } else {
                asm volatile("s_waitcnt vmcnt(4)" ::: "memory");
            }
        } else {
            asm volatile("s_waitcnt vmcnt(0)" ::: "memory");
        }
        __builtin_amdgcn_s_barrier();

        const bf16x8 af = *(const bf16x8*)&As[buf][l16 * 32 + quad * 8];
        bf16x8 bfr[4];
#pragma unroll
        for (int j = 0; j < 4; ++j)
            bfr[j] = *(const bf16x8*)&Ws[buf][(w * 64 + j * 16 + l16) * 32 + quad * 8];
#pragma unroll
        for (int j = 0; j < 4; ++j)
            acc[j] = __builtin_amdgcn_mfma_f32_16x16x32_bf16(af, bfr[j], acc[j], 0, 0, 0);

        asm volatile("s_waitcnt lgkmcnt(0)" ::: "memory");
        __builtin_amdgcn_s_barrier();
    }

    float s[4], q2[4];
#pragma unroll
    for (int reg = 0; reg < 4; ++reg) {
        float sv = (acc[0][reg] + acc[1][reg]) + (acc[2][reg] + acc[3][reg]);
        float qv = (acc[0][reg] * acc[0][reg] + acc[1][reg] * acc[1][reg]) +
                   (acc[2][reg] * acc[2][reg] + acc[3][reg] * acc[3][reg]);
#pragma unroll
        for (int off = 1; off < 16; off <<= 1) {
            sv += __shfl_xor(sv, off);
            qv += __shfl_xor(qv, off);
        }
        s[reg] = sv; q2[reg] = qv;
    }
    if (l16 == 0) {
#pragma unroll
        for (int reg = 0; reg < 4; ++reg) {
            redS[w][quad * 4 + reg] = s[reg];
            redQ[w][quad * 4 + reg] = q2[reg];
        }
    }
    __syncthreads();

#pragma unroll
    for (int reg = 0; reg < 4; ++reg) {
        const int r = quad * 4 + reg;
        const float sum = (redS[0][r] + redS[1][r]) + (redS[2][r] + redS[3][r]);
        const float sq  = (redQ[0][r] + redQ[1][r]) + (redQ[2][r] + redQ[3][r]);
        const float mu  = sum * (1.0f / DC);
        const float var = sq * (1.0f / DC) - mu * mu;
        const float rstd = rsqrtf(var + 1e-5f);
#pragma unroll
        for (int j = 0; j < 4; ++j) {
            const int col = w * 64 + j * 16 + l16;
            const float val = (acc[j][reg] - mu) * rstd * g[col] + bta[col];
            outb[(size_t)(m0 + r) * DC + col] = f2bf(val);
        }
    }
}

// ---------------------------------------------------------------------------
// MFMA flash attention (round-10/12 version — session best: 44.7-46.0us,
// total 208.8us). j = 31-(b>>5) LPT mapping RESTORED.
// [r21: "balanced" remap (j from {2g,31-2g,2g+1,30-2g}) regressed 44.7->49.7,
//  Occ 28->22 — the b=b0 (mod 256) co-location model is wrong; the original
//  interleaved LPT mapping balances better under the real dispatcher.]
// Counted-wait barrier (lgkmcnt(0)+raw s_barrier); stride-64 XOR-swizzled
// K/V/P LDS (conflicts=0, 40960 B = 4 blocks/CU); T14 reg-prefetch + dbuf
// Ks/Vs + setprio. 1024 blocks = 32 heads x 32 q-tiles of 64 rows.
// [r20: vf hoist spilled under launch_bounds(256,4) — keep vf after softmax.]
// [r19: counted barrier neutral — stall is the per-wave serial chain.]
// [r14: direct-global K/V regressed 3x — KEEP LDS staging.]
// [r12: 32 q-rows/wave regressed — keep 64-row q-tiles + 1024 blocks.]
// ---------------------------------------------------------------------------
__global__ __launch_bounds__(256, 4) void flash_mfma(
    const unsigned short* __restrict__ q, const unsigned short* __restrict__ k,
    const unsigned short* __restrict__ vt, unsigned short* __restrict__ o)
{
    __shared__ unsigned short Ks[2][64 * 64];
    __shared__ unsigned short Vs[2][64 * 64];
    __shared__ unsigned short Ps[64 * 64];

    const int bh = blockIdx.x & 31;
    const int j  = 31 - (blockIdx.x >> 5);     // LPT: heaviest first
    const int q0 = j * 64;
    const int tid = threadIdx.x;
    const int w = tid >> 6, lane = tid & 63;
    const int l16 = lane & 15, quad = lane >> 4;
    const int rbase = q0 + w * 16;
    const int xh = l16 & 7;

    bf16x8 qf[2];
#pragma unroll
    for (int kk = 0; kk < 2; ++kk)
        qf[kk] = *(const bf16x8*)(q + ((size_t)bh * T_SEQ + rbase + l16) * HDIM + kk * 32 + quad * 8);

    f32x4 of[4];
    float lrow[4];
#pragma unroll
    for (int dt = 0; dt < 4; ++dt) of[dt] = (f32x4){0.f, 0.f, 0.f, 0.f};
#pragma unroll
    for (int r = 0; r < 4; ++r) lrow[r] = 0.f;

    const int ldr = tid >> 2;
    const int ldc = (tid & 3) * 16;
    // Swizzled store offsets for this lane's two b128 stores (groups g, g+1).
    const int sg0 = (((ldc >> 3) + 0) ^ (ldr & 7)) << 3;
    const int sg1 = (((ldc >> 3) + 1) ^ (ldr & 7)) << 3;
    const unsigned short* kgb = k + ((size_t)bh * T_SEQ + ldr) * HDIM + ldc;
    const unsigned short* vgb = vt + ((size_t)bh * HDIM + ldr) * T_SEQ + ldc;

    // Prefetch tile 0 into registers (T14 issue-early).
    bf16x8 kr0 = *(const bf16x8*)kgb;
    bf16x8 kr1 = *(const bf16x8*)(kgb + 8);
    bf16x8 vr0 = *(const bf16x8*)vgb;
    bf16x8 vr1 = *(const bf16x8*)(vgb + 8);

    const int kend = (j + 1) * 64;
    int buf = 0;
    for (int k0 = 0; k0 < kend; k0 += 64, buf ^= 1) {
        // Write staged regs to LDS (write-late half of T14), swizzled.
        *(bf16x8*)&Ks[buf][ldr * 64 + sg0] = kr0;
        *(bf16x8*)&Ks[buf][ldr * 64 + sg1] = kr1;
        *(bf16x8*)&Vs[buf][ldr * 64 + sg0] = vr0;
        *(bf16x8*)&Vs[buf][ldr * 64 + sg1] = vr1;
        // Issue next-tile loads; they stay in flight ACROSS the barrier.
        if (k0 + 64 < kend) {
            const unsigned short* kg = kgb + (size_t)(k0 + 64) * HDIM;
            const unsigned short* vg = vgb + (k0 + 64);
            kr0 = *(const bf16x8*)kg;
            kr1 = *(const bf16x8*)(kg + 8);
            vr0 = *(const bf16x8*)vg;
            vr1 = *(const bf16x8*)(vg + 8);
        }
        // Counted-wait barrier: ds ops drained, global loads NOT (r19).
        asm volatile("s_waitcnt lgkmcnt(0)" ::: "memory");
        __builtin_amdgcn_s_barrier();

        bf16x8 kf[4][2];
#pragma unroll
        for (int nt = 0; nt < 4; ++nt)
#pragma unroll
            for (int kk = 0; kk < 2; ++kk)
                kf[nt][kk] = *(const bf16x8*)&Ks[buf][(nt * 16 + l16) * 64 +
                                                     (((kk * 4 + quad) ^ xh) << 3)];

        f32x4 sf[4];
        __builtin_amdgcn_s_setprio(1);
#pragma unroll
        for (int nt = 0; nt < 4; ++nt) {
            sf[nt] = (f32x4){0.f, 0.f, 0.f, 0.f};
#pragma unroll
            for (int kk = 0; kk < 2; ++kk)
                sf[nt] = __builtin_amdgcn_mfma_f32_16x16x32_bf16(qf[kk], kf[nt][kk], sf[nt], 0, 0, 0);
        }
        __builtin_amdgcn_s_setprio(0);

        const bool need_mask = (k0 + 63) > rbase;
#pragma unroll
        for (int reg = 0; reg < 4; ++reg) {
            float a0 = sf[0][reg], a1 = sf[1][reg], a2 = sf[2][reg], a3 = sf[3][reg];
            if (need_mask) {
                const int tq = rbase + quad * 4 + reg;
                if (k0 +      l16 > tq) a0 = -1e30f;
                if (k0 + 16 + l16 > tq) a1 = -1e30f;
                if (k0 + 32 + l16 > tq) a2 = -1e30f;
                if (k0 + 48 + l16 > tq) a3 = -1e30f;
            }
            union { float f; unsigned u; } u0, u1, u2, u3;
            u0.f = exp2f(a0); u1.f = exp2f(a1);
            u2.f = exp2f(a2); u3.f = exp2f(a3);
            // P[prow][col=nt*16+l16] -> swizzled: prow*64 + (g^(prow&7))*8 + (l16&7),
            // g = nt*2 + (l16>>3).
            const int prow = w * 16 + quad * 4 + reg;
            const int pr7 = prow & 7;
            const int pb = prow * 64 + (l16 & 7);
            const int g0 = l16 >> 3;
            Ps[pb + (((0 + g0) ^ pr7) << 3)] = (unsigned short)(u0.u >> 16);
            Ps[pb + (((2 + g0) ^ pr7) << 3)] = (unsigned short)(u1.u >> 16);
            Ps[pb + (((4 + g0) ^ pr7) << 3)] = (unsigned short)(u2.u >> 16);
            Ps[pb + (((6 + g0) ^ pr7) << 3)] = (unsigned short)(u3.u >> 16);
            u0.u &= 0xffff0000u; u1.u &= 0xffff0000u;
            u2.u &= 0xffff0000u; u3.u &= 0xffff0000u;
            lrow[reg] += (u0.f + u1.f) + (u2.f + u3.f);
        }

        bf16x8 vf[4][2];
#pragma unroll
        for (int dt = 0; dt < 4; ++dt)
#pragma unroll
            for (int kk = 0; kk < 2; ++kk)
                vf[dt][kk] = *(const bf16x8*)&Vs[buf][(dt * 16 + l16) * 64 +
                                                     (((kk * 4 + quad) ^ xh) << 3)];

        bf16x8 pf[2];
#pragma unroll
        for (int kk = 0; kk < 2; ++kk)
            pf[kk] = *(const bf16x8*)&Ps[(w * 16 + l16) * 64 +
                                         (((kk * 4 + quad) ^ xh) << 3)];
        __builtin_amdgcn_s_setprio(1);
#pragma unroll
        for (int dt = 0; dt < 4; ++dt)
#pragma unroll
            for (int kk = 0; kk < 2; ++kk)
                of[dt] = __builtin_amdgcn_mfma_f32_16x16x32_bf16(pf[kk], vf[dt][kk], of[dt], 0, 0, 0);
        __builtin_amdgcn_s_setprio(0);
    }

    const int b = bh >> 4, h = bh & 15;
#pragma unroll
    for (int reg = 0; reg < 4; ++reg) {
        float l = lrow[reg];
        l += __shfl_xor(l, 1);
        l += __shfl_xor(l, 2);
        l += __shfl_xor(l, 4);
        l += __shfl_xor(l, 8);
        const float inv = 1.0f / l;
        const int t = rbase + quad * 4 + reg;
#pragma unroll
        for (int dt = 0; dt < 4; ++dt)
            o[((size_t)b * T_SEQ + t) * (NH * HDIM) + h * HDIM + dt * 16 + l16] =
                f2bf(of[dt][reg] * inv);
    }
}

// ---------------------------------------------------------------------------
extern "C" void kernel_launch(void* const* d_in, const int* in_sizes, int n_in,
                              void* d_out, int out_size, void* d_ws, size_t ws_size,
                              hipStream_t stream)
{
    (void)in_sizes; (void)n_in; (void)out_size; (void)ws_size;

    const float* x        = (const float*)d_in[0];
    const float* W_q      = (const float*)d_in[1];
    const float* b_q      = (const float*)d_in[2];
    const float* W_kvl    = (const float*)d_in[3];
    const float* b_kvl    = (const float*)d_in[4];
    const float* ts_scale = (const float*)d_in[5];
    const float* ts_shift = (const float*)d_in[6];
    const float* W_comp   = (const float*)d_in[7];
    const float* W_exp    = (const float*)d_in[8];
    const float* ln_g     = (const float*)d_in[9];
    const float* ln_b     = (const float*)d_in[10];
    const float* W_fkv    = (const float*)d_in[11];
    const float* b_fkv    = (const float*)d_in[12];
    const float* W_out    = (const float*)d_in[13];
    const float* b_out    = (const float*)d_in[14];
    float* out = (float*)d_out;

    char* p = (char*)d_ws;
    unsigned short* xb     = (unsigned short*)p;             p += 8  * 1024 * 1024;
    unsigned short* wqh    = (unsigned short*)p;             p += 2  * 1024 * 1024;
    unsigned short* wkvlh  = (unsigned short*)p;             p += 1  * 1024 * 1024;
    unsigned short* wcomph = (unsigned short*)p;             p += 256 * 1024;
    unsigned short* wexpTh = (unsigned short*)p;             p += 256 * 1024;
    unsigned short* wfkvh  = (unsigned short*)p;             p += 2  * 1024 * 1024;
    unsigned short* wouth  = (unsigned short*)p;             p += 2  * 1024 * 1024;
    unsigned short* qh     = (unsigned short*)p;             p += 8  * 1024 * 1024;
    unsigned short* kh     = (unsigned short*)p;             p += 8  * 1024 * 1024;
    unsigned short* vth    = (unsigned short*)p;             p += 8  * 1024 * 1024;
    unsigned short* xt     = (unsigned short*)p;             p += 4  * 1024 * 1024;
    unsigned short* cbh    = (unsigned short*)p;             p += 2  * 1024 * 1024;
    unsigned short* wcombh = (unsigned short*)p;             p += 4  * 1024 * 1024;
    unsigned short* ob     = (unsigned short*)p;             p += 8  * 1024 * 1024;
    float2*         tab    = (float2*)p;                     p += 512 * 1024;

    const dim3 blk(256);

    cvt_bf16<<<1024, blk, 0, stream>>>(x, W_q, W_kvl, W_comp, W_exp, W_fkv, W_out,
                                       xb, wqh, wkvlh, wcomph, wexpTh, wfkvh, wouth,
                                       tab);

    gemm_wcomb<<<dim3(32, 4), blk, 0, stream>>>(
        wfkvh, wexpTh, wcombh);

    gemm_qxt<<<dim3(32, 24), blk, 0, stream>>>(
        xb, wqh, wkvlh, b_q, b_kvl, ts_scale, ts_shift, tab, qh, xt);

    gemm_c_ln<<<256, blk, 0, stream>>>(
        xt, wcomph, ln_g, ln_b, cbh);

    gemm_kv<<<dim3(32, 32), blk, 0, stream>>>(
        cbh, wcombh, b_fkv, tab, kh, vth);

    flash_mfma<<<1024, blk, 0, stream>>>(qh, kh, vth, ob);

    gemm_out<<<dim3(32, 16), blk, 0, stream>>>(
        ob, wouth, b_out, out);
}